// Round 12
// baseline (240.444 us; speedup 1.0000x reference)
//
#include <hip/hip_runtime.h>
#include <hip/hip_bf16.h>
#include <math.h>

// ---------- types ----------
typedef __bf16 bf16x8 __attribute__((ext_vector_type(8)));
typedef float  f32x4  __attribute__((ext_vector_type(4)));

#define B_ROWS 8192
#define HSZ    1024

#define GLOAD16(gsrc, ldst)                                                          \
  __builtin_amdgcn_global_load_lds((const __attribute__((address_space(1))) void*)(gsrc), \
                                   (__attribute__((address_space(3))) void*)(ldst),  \
                                   16, 0, 0)

__device__ inline unsigned short f2bf(float f) {
  union { float f; unsigned u; } x; x.f = f;
  unsigned r = x.u + 0x7fffu + ((x.u >> 16) & 1u);   // RNE
  return (unsigned short)(r >> 16);
}

__device__ inline float sigm(float x) { return 1.0f / (1.0f + __expf(-x)); }

// ---------- kernel 0: fp32 -> bf16 conversion + T precompute (16B stores) ----------
__global__ void k_convert(const float* __restrict__ inp,   // [8192][1025]
                          const float* __restrict__ h,     // [8192][1024]
                          const float* __restrict__ Wl,    // [4096][2048]
                          const float* __restrict__ Wd,    // [1024][1024]
                          unsigned short* __restrict__ comb, // [8192][2048]
                          unsigned short* __restrict__ Wlb,  // [4096][2048]
                          unsigned short* __restrict__ hb,   // [8192][1024]
                          unsigned short* __restrict__ Wdb,  // [1024][1024]
                          float* __restrict__ Tm1) {         // [8192] = T-1
  const long stride = (long)gridDim.x * blockDim.x;
  const long tid0 = (long)blockIdx.x * blockDim.x + threadIdx.x;

#define CNV8(dst, s0, s1) { ushort4 u0, u1;                                   \
    u0.x = f2bf(s0.x); u0.y = f2bf(s0.y); u0.z = f2bf(s0.z); u0.w = f2bf(s0.w); \
    u1.x = f2bf(s1.x); u1.y = f2bf(s1.y); u1.z = f2bf(s1.z); u1.w = f2bf(s1.w); \
    *(ushort4*)(dst) = u0; *(ushort4*)((dst) + 4) = u1; }

  for (long i = tid0; i < (long)B_ROWS * HSZ / 8; i += stride) {
    float4 v0 = ((const float4*)h)[i * 2], v1 = ((const float4*)h)[i * 2 + 1];
    CNV8(hb + i * 8, v0, v1);
  }
  for (long i = tid0; i < (long)B_ROWS * HSZ / 8; i += stride) {
    long e = i * 8; long b = e >> 10; long c = e & 1023;
    const float* s = inp + b * 1025 + c;
    float4 v0 = *(const float4*)s, v1 = *(const float4*)(s + 4);
    CNV8(comb + b * 2048 + c, v0, v1);
  }
  for (long i = tid0; i < 4096L * 2048 / 8; i += stride) {
    float4 v0 = ((const float4*)Wl)[i * 2], v1 = ((const float4*)Wl)[i * 2 + 1];
    CNV8(Wlb + i * 8, v0, v1);
  }
  for (long i = tid0; i < 1024L * 1024 / 8; i += stride) {
    float4 v0 = ((const float4*)Wd)[i * 2], v1 = ((const float4*)Wd)[i * 2 + 1];
    CNV8(Wdb + i * 8, v0, v1);
  }
  for (long i = tid0; i < B_ROWS; i += stride) {
    float dt = inp[i * 1025 + 1024];
    Tm1[i] = 1.0f / logf(dt + 2.7183f) - 1.0f;
  }
#undef CNV8
}

// ======================================================================
// Shared 128x128 free-running GEMM skeleton: 4 waves (2Mx2N, 64x64/wave),
// ring-3 LDS (3 x 16KB -> 3 blocks/CU co-resident, async inter-block overlap),
// one "memory"-fenced counted vmcnt(4) + one s_barrier per K32-tile, open
// region {stage(t+2); 8 ds_reads; 16 MFMA} for compiler fine-grained lgkm.
// Ledger: at tile-t head outstanding = {stage(t),stage(t+1)} = 8 -> vmcnt(4)
// publishes t, never drains. stage(t+2) -> slot (t-1)%3, freed by barrier.
// ======================================================================

// ---------- kernel 1: C_ST GEMM (8192x1024x1024) + h_adj epilogue ----------
#define NT1 32   // 1024/32
__global__ __launch_bounds__(256, 3)
void k_gemm1_fr(const unsigned short* __restrict__ A,   // hb  [8192][1024]
                const unsigned short* __restrict__ Bm,  // Wdb [1024][1024]
                const float* __restrict__ h,            // h_cur f32
                const float* __restrict__ bd,           // b_desc [1024]
                const float* __restrict__ Tm1,
                unsigned short* __restrict__ comb) {
  __shared__ __align__(16) unsigned short lds[3][8192];   // [A 128x32 | B 128x32]

  const int tid = threadIdx.x;
  const int lane = tid & 63;
  const int wid = tid >> 6;
  const int wr = wid >> 1, wc = wid & 1;

  // L2 map: XCD owns 8 bRow x 8 bCol (A-slice 2MB + B 2MB = L2-fit)
  const int bid = blockIdx.x;          // 512 blocks
  const int xcd = bid & 7;
  const int ii = bid >> 3;             // 0..63
  const int bRow = xcd * 8 + (ii & 7); // 0..63
  const int bCol = ii >> 3;            // 0..7

  const int sr = tid >> 2;             // 0..63
  const int swsel = (sr >> 1) & 3;
  const int gk = ((tid & 3) ^ swsel) << 3;
  const unsigned short* aS0 = A + (long)(bRow * 128 + sr) * 1024 + gk;
  const unsigned short* aS1 = A + (long)(bRow * 128 + 64 + sr) * 1024 + gk;
  const unsigned short* bS0 = Bm + (long)(bCol * 128 + sr) * 1024 + gk;
  const unsigned short* bS1 = Bm + (long)(bCol * 128 + 64 + sr) * 1024 + gk;

#define STG1(slot, tt) {                                                  \
    GLOAD16(aS0 + (long)(tt) * 32, &lds[slot][0    + tid * 8]);           \
    GLOAD16(aS1 + (long)(tt) * 32, &lds[slot][2048 + tid * 8]);           \
    GLOAD16(bS0 + (long)(tt) * 32, &lds[slot][4096 + tid * 8]);           \
    GLOAD16(bS1 + (long)(tt) * 32, &lds[slot][6144 + tid * 8]); }

  const int fr = lane & 15, q = lane >> 4;
  int offA[4], offB[4];
#pragma unroll
  for (int m = 0; m < 4; m++) {
    const int row = wr * 64 + m * 16 + fr;
    offA[m] = row * 32 + ((q ^ ((row >> 1) & 3)) << 3);
  }
#pragma unroll
  for (int n = 0; n < 4; n++) {
    const int row = wc * 64 + n * 16 + fr;
    offB[n] = 4096 + row * 32 + ((q ^ ((row >> 1) & 3)) << 3);
  }

  f32x4 acc[4][4] = {};

  STG1(0, 0); STG1(1, 1);

#define BODY1(t, SLOT, VM)                                                          \
  {                                                                                 \
    asm volatile("s_waitcnt vmcnt(" #VM ")" ::: "memory");                          \
    __builtin_amdgcn_s_barrier();                                                   \
    if ((t) + 2 < NT1) STG1(((t) + 2) % 3, (t) + 2);                                \
    const unsigned short* buf = &lds[SLOT][0];                                      \
    bf16x8 aF[4], bF[4];                                                            \
    _Pragma("unroll")                                                               \
    for (int n = 0; n < 4; n++) bF[n] = *(const bf16x8*)(buf + offB[n]);            \
    _Pragma("unroll")                                                               \
    for (int m = 0; m < 4; m++) aF[m] = *(const bf16x8*)(buf + offA[m]);            \
    __builtin_amdgcn_s_setprio(1);                                                  \
    _Pragma("unroll")                                                               \
    for (int m = 0; m < 4; m++)                                                     \
      _Pragma("unroll")                                                             \
      for (int n = 0; n < 4; n++)                                                   \
        acc[m][n] = __builtin_amdgcn_mfma_f32_16x16x32_bf16(aF[m], bF[n], acc[m][n], 0, 0, 0); \
    __builtin_amdgcn_s_setprio(0);                                                  \
  }

  for (int t = 0; t < 30; t += 3) {
    BODY1(t,     0, 4);
    BODY1(t + 1, 1, 4);
    BODY1(t + 2, 2, 4);
  }
  BODY1(30, 0, 4);
  BODY1(31, 1, 0);
#undef BODY1

  const int cr = (lane >> 4) * 4;
  const int cc = lane & 15;
#pragma unroll
  for (int m = 0; m < 4; m++)
#pragma unroll
    for (int n = 0; n < 4; n++) {
      const int col = bCol * 128 + wc * 64 + n * 16 + cc;
#pragma unroll
      for (int r = 0; r < 4; r++) {
        const int row = bRow * 128 + wr * 64 + m * 16 + cr + r;
        float v = acc[m][n][r] + bd[col];
        float cst = tanhf(v);
        float hadj = h[(long)row * HSZ + col] + Tm1[row] * cst;
        comb[(long)row * 2048 + 1024 + col] = f2bf(hadj);
      }
    }
}

// ---------- kernel 2: gates GEMM (8192 x [32j x 4g] x 2048) + LSTM epilogue ----------
// B-tile 128 rows = gate-interleaved: local row rl -> gate=(rl>>4)&3,
// j = bCol*32 + (rl>>6)*16 + (rl&15). Frag n == gate n (epilogue stays fused).
#define NT2 64   // 2048/32
__global__ __launch_bounds__(256, 3)
void k_gemm2_fr(const unsigned short* __restrict__ A,   // comb [8192][2048]
                const unsigned short* __restrict__ Bm,  // Wlb  [4096][2048]
                const float* __restrict__ bl,           // b_layers [4096]
                const float* __restrict__ c_cur,        // f32 [8192][1024]
                float* __restrict__ out) {              // h_next | c_next (f32)
  __shared__ __align__(16) unsigned short lds[3][8192];   // [A 128x32 | B 128x32]

  const int tid = threadIdx.x;
  const int lane = tid & 63;
  const int wid = tid >> 6;
  const int wr = wid >> 1, wc = wid & 1;

  // L2 map: XCD owns 4 bCols (B 2MB L2-resident); quads of bCol share bRow window.
  const int bid = blockIdx.x;            // 2048 blocks
  const int xcd = bid & 7;
  const int ii = bid >> 3;               // 0..255
  const int bCol = xcd * 4 + (ii & 3);   // 0..31
  const int bRow = ii >> 2;              // 0..63

  const int sr = tid >> 2;               // 0..63
  const int swsel = (sr >> 1) & 3;
  const int gk = ((tid & 3) ^ swsel) << 3;
  const unsigned short* aS0 = A + (long)(bRow * 128 + sr) * 2048 + gk;
  const unsigned short* aS1 = A + (long)(bRow * 128 + 64 + sr) * 2048 + gk;
  const int grow0 = ((sr >> 4) & 3) * 1024 + bCol * 32 + (sr & 15);        // rl = sr
  const unsigned short* bS0 = Bm + (long)grow0 * 2048 + gk;
  const unsigned short* bS1 = Bm + (long)(grow0 + 16) * 2048 + gk;          // rl = 64+sr

#define STG2(slot, tt) {                                                  \
    GLOAD16(aS0 + (long)(tt) * 32, &lds[slot][0    + tid * 8]);           \
    GLOAD16(aS1 + (long)(tt) * 32, &lds[slot][2048 + tid * 8]);           \
    GLOAD16(bS0 + (long)(tt) * 32, &lds[slot][4096 + tid * 8]);           \
    GLOAD16(bS1 + (long)(tt) * 32, &lds[slot][6144 + tid * 8]); }

  const int fr = lane & 15, q = lane >> 4;
  int offA[4], offB[4];
#pragma unroll
  for (int m = 0; m < 4; m++) {
    const int row = wr * 64 + m * 16 + fr;
    offA[m] = row * 32 + ((q ^ ((row >> 1) & 3)) << 3);
  }
#pragma unroll
  for (int n = 0; n < 4; n++) {
    const int row = wc * 64 + n * 16 + fr;   // gate n, j-part wc*16+fr
    offB[n] = 4096 + row * 32 + ((q ^ ((row >> 1) & 3)) << 3);
  }

  f32x4 acc[4][4] = {};   // [m][gate]

  STG2(0, 0); STG2(1, 1);

#define BODY2(t, SLOT, VM)                                                          \
  {                                                                                 \
    asm volatile("s_waitcnt vmcnt(" #VM ")" ::: "memory");                          \
    __builtin_amdgcn_s_barrier();                                                   \
    if ((t) + 2 < NT2) STG2(((t) + 2) % 3, (t) + 2);                                \
    const unsigned short* buf = &lds[SLOT][0];                                      \
    bf16x8 aF[4], bF[4];                                                            \
    _Pragma("unroll")                                                               \
    for (int n = 0; n < 4; n++) bF[n] = *(const bf16x8*)(buf + offB[n]);            \
    _Pragma("unroll")                                                               \
    for (int m = 0; m < 4; m++) aF[m] = *(const bf16x8*)(buf + offA[m]);            \
    __builtin_amdgcn_s_setprio(1);                                                  \
    _Pragma("unroll")                                                               \
    for (int m = 0; m < 4; m++)                                                     \
      _Pragma("unroll")                                                             \
      for (int n = 0; n < 4; n++)                                                   \
        acc[m][n] = __builtin_amdgcn_mfma_f32_16x16x32_bf16(aF[m], bF[n], acc[m][n], 0, 0, 0); \
    __builtin_amdgcn_s_setprio(0);                                                  \
  }

  for (int t = 0; t < 63; t += 3) {
    BODY2(t,     0, 4);
    BODY2(t + 1, 1, 4);
    BODY2(t + 2, 2, 4);
  }
  BODY2(63, 0, 0);
#undef BODY2

  // ---- fused LSTM epilogue ----
  const int cr = (lane >> 4) * 4;
  const int cc = lane & 15;
  const int j = bCol * 32 + wc * 16 + cc;       // 0..1023
#pragma unroll
  for (int m = 0; m < 4; m++) {
#pragma unroll
    for (int r = 0; r < 4; r++) {
      const int row = bRow * 128 + wr * 64 + m * 16 + cr + r;
      float iv = sigm(acc[m][0][r] + bl[j]);
      float fv = sigm(acc[m][1][r] + bl[1024 + j]);
      float ov = sigm(acc[m][2][r] + bl[2048 + j]);
      float gv = tanhf(acc[m][3][r] + bl[3072 + j]);
      float cn = fv * c_cur[(long)row * HSZ + j] + iv * gv;
      float hn = ov * tanhf(cn);
      out[(long)row * HSZ + j] = hn;                         // h_next
      out[(long)B_ROWS * HSZ + (long)row * HSZ + j] = cn;    // c_next
    }
  }
}

// ---------- launch ----------
extern "C" void kernel_launch(void* const* d_in, const int* in_sizes, int n_in,
                              void* d_out, int out_size, void* d_ws, size_t ws_size,
                              hipStream_t stream) {
  const float* inp = (const float*)d_in[0];   // input_tensor [8192][1025]
  const float* h   = (const float*)d_in[1];   // h_cur
  const float* c   = (const float*)d_in[2];   // c_cur
  const float* Wl  = (const float*)d_in[3];   // W_layers [4096][2048]
  const float* bl  = (const float*)d_in[4];   // b_layers [4096]
  const float* Wd  = (const float*)d_in[5];   // W_desc [1024][1024]
  const float* bd  = (const float*)d_in[6];   // b_desc [1024]

  char* ws = (char*)d_ws;
  unsigned short* comb = (unsigned short*)(ws);               // 33,554,432 B
  unsigned short* Wlb  = (unsigned short*)(ws + 33554432);    // 16,777,216 B
  unsigned short* hb   = (unsigned short*)(ws + 50331648);    // 16,777,216 B
  unsigned short* Wdb  = (unsigned short*)(ws + 67108864);    //  2,097,152 B
  float*          Tm1  = (float*)(ws + 69206016);             //     32,768 B
  float*          out  = (float*)d_out;                       // f32 outputs

  hipLaunchKernelGGL(k_convert, dim3(2048), dim3(256), 0, stream,
                     inp, h, Wl, Wd, comb, Wlb, hb, Wdb, Tm1);
  hipLaunchKernelGGL(k_gemm1_fr, dim3(512), dim3(256), 0, stream,
                     hb, Wdb, h, bd, Tm1, comb);
  hipLaunchKernelGGL(k_gemm2_fr, dim3(2048), dim3(256), 0, stream,
                     comb, Wlb, bl, c, out);
}